// Round 5
// baseline (1333.660 us; speedup 1.0000x reference)
//
#include <hip/hip_runtime.h>

#define NC 50000
#define NG 3000
#define D  64

// ======================= prelude =======================

__global__ __launch_bounds__(256) void weights_kernel(
    const float* __restrict__ cj_cell, const float* __restrict__ mask_exp,
    const float* __restrict__ cj_gene, const float* __restrict__ mask_rev,
    const float* __restrict__ cjj_gene, const float* __restrict__ mask_gg,
    float* __restrict__ w_cell, float* __restrict__ w_gene_rev, float* __restrict__ w_gene_gg)
{
    int i = blockIdx.x * blockDim.x + threadIdx.x;
    if (i < NC) w_cell[i] = cj_cell[i] * mask_exp[i];
    if (i < NG) {
        w_gene_rev[i] = cj_gene[i] * mask_rev[i];
        w_gene_gg[i]  = cjj_gene[i] * mask_gg[i];
    }
}

// Histogram with LDS aggregation, whole range fits LDS (NG == 3000 -> 12 KB)
__global__ __launch_bounds__(256) void hist_lds_kernel(
    const int* __restrict__ dst, int* __restrict__ counts, int nedges)
{
    __shared__ int h[NG];
    for (int i = threadIdx.x; i < NG; i += 256) h[i] = 0;
    __syncthreads();
    for (long long e = (long long)blockIdx.x * 256 + threadIdx.x; e < nedges;
         e += (long long)gridDim.x * 256) {
        const int d = dst[e];
        if (d >= 0 && d < NG) atomicAdd(&h[d], 1);
    }
    __syncthreads();
    for (int i = threadIdx.x; i < NG; i += 256) {
        int v = h[i];
        if (v) atomicAdd(&counts[i], v);
    }
}

// Sliced LDS histogram for large dst range (NC): 8 slices of DIV bins each.
// dst stream is nontemporal (read 8x, must not thrash L2).
template <int DIV>
__global__ __launch_bounds__(256) void hist_lds_sliced_kernel(
    const int* __restrict__ dst, int* __restrict__ counts, int nedges)
{
    __shared__ int h[DIV];
    for (int i = threadIdx.x; i < DIV; i += 256) h[i] = 0;
    __syncthreads();
    const int slice = blockIdx.x & 7;
    const int bgrp  = blockIdx.x >> 3;
    const int nb    = gridDim.x >> 3;
    const int lo = slice * DIV;
    const int hi = lo + DIV;
    for (long long e = (long long)bgrp * 256 + threadIdx.x; e < nedges;
         e += (long long)nb * 256) {
        const int d = __builtin_nontemporal_load(dst + e);
        if (d >= lo && d < hi) atomicAdd(&h[d - lo], 1);
    }
    __syncthreads();
    for (int i = threadIdx.x; i < DIV; i += 256) {
        int v = h[i];
        if (v) atomicAdd(&counts[lo + i], v);
    }
}

// Three exclusive scans in one launch: block b scans array b.
__global__ __launch_bounds__(1024) void scan3_kernel(
    int* __restrict__ c0, int* __restrict__ o0, int* __restrict__ u0, int n0,
    int* __restrict__ c1, int* __restrict__ o1, int* __restrict__ u1, int n1,
    int* __restrict__ c2, int* __restrict__ o2, int* __restrict__ u2, int n2)
{
    const int* counts; int* offs; int* cursor; int n;
    if (blockIdx.x == 0)      { counts = c0; offs = o0; cursor = u0; n = n0; }
    else if (blockIdx.x == 1) { counts = c1; offs = o1; cursor = u1; n = n1; }
    else                      { counts = c2; offs = o2; cursor = u2; n = n2; }

    __shared__ int wtot[16];
    __shared__ int woff[16];
    __shared__ int ctot_s;
    __shared__ int carry_s;
    const int tid  = threadIdx.x;
    const int lane = tid & 63;
    const int wid  = tid >> 6;
    if (tid == 0) carry_s = 0;
    __syncthreads();
    for (int base = 0; base < n; base += 1024) {
        int i = base + tid;
        int v = (i < n) ? counts[i] : 0;
        int incl = v;
        #pragma unroll
        for (int d = 1; d < 64; d <<= 1) {
            int t = __shfl_up(incl, d);
            if (lane >= d) incl += t;
        }
        if (lane == 63) wtot[wid] = incl;
        __syncthreads();
        if (wid == 0) {
            int t = (lane < 16) ? wtot[lane] : 0;
            #pragma unroll
            for (int d = 1; d < 16; d <<= 1) {
                int u = __shfl_up(t, d);
                if (lane >= d) t += u;
            }
            if (lane < 16) woff[lane] = t - wtot[lane];
            if (lane == 15) ctot_s = t;
        }
        __syncthreads();
        int excl = incl - v + woff[wid] + carry_s;
        if (i < n) { offs[i] = excl; cursor[i] = excl; }
        __syncthreads();
        if (tid == 0) carry_s += ctot_s;
        __syncthreads();
    }
    if (tid == 0) offs[n] = carry_s;
}

// ======================= dst-sliced fill, nontemporal dst stream =======================
// 8 slice-groups; group s fills only edges whose dst is in [s*DIV, (s+1)*DIV).
// dst is read 8x -> nontemporal so it does NOT evict the per-XCD L2-resident
// bucket-slice write lines (~1.5 MB) + cursor slice. Bucket store is
// bounds-guarded so no replay/ordering anomaly can write outside ws.
template <int DIV>
__global__ __launch_bounds__(256) void fill_sliced_kernel(
    const int* __restrict__ src, const int* __restrict__ dst,
    int* __restrict__ cursor, int* __restrict__ bucket, int nedges, int ntot)
{
    const int slice = blockIdx.x & 7;
    const int bgrp  = blockIdx.x >> 3;
    const int nb    = gridDim.x >> 3;
    const int lo = slice * DIV;
    const int hi = lo + DIV;
    for (long long e = (long long)bgrp * 256 + threadIdx.x; e < nedges;
         e += (long long)nb * 256) {
        const int d = __builtin_nontemporal_load(dst + e);
        if (d >= lo && d < hi) {
            const int s = src[e];
            int pos = atomicAdd(&cursor[d], 1);
            if (pos >= 0 && pos < ntot) bucket[pos] = s;
        }
    }
}

// Unsliced fill for the small gg relation (bucket region 400 KB, L2-resident).
__global__ __launch_bounds__(256) void fill_kernel(
    const int* __restrict__ src, const int* __restrict__ dst,
    int* __restrict__ cursor, int* __restrict__ bucket, int nedges, int ntot)
{
    for (long long e = (long long)blockIdx.x * 256 + threadIdx.x; e < nedges;
         e += (long long)gridDim.x * 256) {
        int pos = atomicAdd(&cursor[dst[e]], 1);
        if (pos >= 0 && pos < ntot) bucket[pos] = src[e];
    }
}

// ======================= gather =======================
// One wave per dst row; 4 edges in flight (4 groups of 16 lanes, float4/lane).
template <bool ACC>
__global__ __launch_bounds__(256) void gather_kernel(
    const float* __restrict__ feat, const float* __restrict__ wsrc,
    const float* __restrict__ ci, const int* __restrict__ offs,
    const int* __restrict__ bucket, float* __restrict__ out, int ndst, int ntot,
    float alpha)
{
    const int row = blockIdx.x * 4 + (threadIdx.x >> 6);
    if (row >= ndst) return;
    const int lane = threadIdx.x & 63;
    const int grp  = lane >> 4;
    const int l16  = lane & 15;
    int begin = offs[row], end = offs[row + 1];
    // defensive clamps: stay inside ws even with anomalous offs
    begin = begin < 0 ? 0 : (begin > ntot ? ntot : begin);
    end   = end   < 0 ? 0 : (end   > ntot ? ntot : end);

    float4 acc = make_float4(0.f, 0.f, 0.f, 0.f);
    for (int jj = begin; jj < end; jj += 4) {
        const int  j     = jj + grp;
        const bool valid = (j < end);
        const int  s     = valid ? bucket[j] : 0;
        const float w    = valid ? wsrc[s] : 0.0f;
        const float4 v = *(const float4*)(feat + (size_t)s * D + l16 * 4);
        acc.x += w * v.x; acc.y += w * v.y; acc.z += w * v.z; acc.w += w * v.w;
    }
    #pragma unroll
    for (int off = 16; off < 64; off <<= 1) {
        acc.x += __shfl_xor(acc.x, off);
        acc.y += __shfl_xor(acc.y, off);
        acc.z += __shfl_xor(acc.z, off);
        acc.w += __shfl_xor(acc.w, off);
    }
    if (grp == 0) {
        const float s_ci = ci[row] * alpha;
        float* o = out + (size_t)row * D + l16 * 4;
        float4 r = make_float4(acc.x * s_ci, acc.y * s_ci, acc.z * s_ci, acc.w * s_ci);
        if (ACC) {
            const float4 prev = *(const float4*)o;
            r.x += prev.x; r.y += prev.y; r.z += prev.z; r.w += prev.w;
        }
        *(float4*)o = r;
    }
}

// ======================= fallback (atomic scatter) =======================

__global__ __launch_bounds__(256) void edge_scatter_kernel(
    const float* __restrict__ feat, const float* __restrict__ cj,
    const float* __restrict__ mask, const float* __restrict__ ci,
    const int* __restrict__ src, const int* __restrict__ dst,
    float* __restrict__ out, int nedges, float alpha)
{
    const int lane16 = threadIdx.x & 15;
    const int eloc   = threadIdx.x >> 4;
    const long long e = (long long)blockIdx.x * 16 + eloc;
    if (e >= nedges) return;
    const int s = src[e];
    const int t = dst[e];
    const float w = cj[s] * mask[s] * ci[t] * alpha;
    const float4 v = *(const float4*)(feat + (size_t)s * D + lane16 * 4);
    float* o = out + (size_t)t * D + lane16 * 4;
#if defined(__HIP_DEVICE_COMPILE__)
    unsafeAtomicAdd(o + 0, w * v.x);
    unsafeAtomicAdd(o + 1, w * v.y);
    unsafeAtomicAdd(o + 2, w * v.z);
    unsafeAtomicAdd(o + 3, w * v.w);
#endif
}

// ======================= launch =======================

extern "C" void kernel_launch(void* const* d_in, const int* in_sizes, int n_in,
                              void* d_out, int out_size, void* d_ws, size_t ws_size,
                              hipStream_t stream)
{
    const float* c_feat   = (const float*)d_in[0];
    const float* g_feat   = (const float*)d_in[1];
    const float* cj_cell  = (const float*)d_in[2];
    const float* ci_cell  = (const float*)d_in[3];
    const float* cj_gene  = (const float*)d_in[4];
    const float* ci_gene  = (const float*)d_in[5];
    const float* cjj_gene = (const float*)d_in[6];
    const float* cii_gene = (const float*)d_in[7];
    const float* mask_exp = (const float*)d_in[8];
    const float* mask_rev = (const float*)d_in[9];
    const float* mask_gg  = (const float*)d_in[10];
    const int*   src_cg   = (const int*)d_in[11];
    const int*   dst_cg   = (const int*)d_in[12];
    const int*   src_gc   = (const int*)d_in[13];
    const int*   dst_gc   = (const int*)d_in[14];
    const int*   src_gg   = (const int*)d_in[15];
    const int*   dst_gg   = (const int*)d_in[16];

    const int e_cg = in_sizes[11];
    const int e_gc = in_sizes[13];
    const int e_gg = in_sizes[15];

    float* c_out = (float*)d_out;                   // [NC, D]
    float* g_out = (float*)d_out + (size_t)NC * D;  // [NG, D]

    // ---- workspace layout (int units) ----
    int* ws = (int*)d_ws;
    size_t p = 0;
    int* cnt_cg = ws + p; p += NG;
    int* cnt_gc = ws + p; p += NC;
    int* cnt_gg = ws + p; p += NG;          // counts contiguous -> one memset
    int* off_cg = ws + p; p += NG + 1;
    int* off_gc = ws + p; p += NC + 1;
    int* off_gg = ws + p; p += NG + 1;
    int* cur_cg = ws + p; p += NG;
    int* cur_gc = ws + p; p += NC;
    int* cur_gg = ws + p; p += NG;
    float* w_cell     = (float*)(ws + p); p += NC;
    float* w_gene_rev = (float*)(ws + p); p += NG;
    float* w_gene_gg  = (float*)(ws + p); p += NG;
    int* bkt_cg = ws + p; p += e_cg;
    int* bkt_gc = ws + p; p += e_gc;
    int* bkt_gg = ws + p; p += e_gg;
    const size_t need = p * sizeof(int);

    if (need > ws_size) {
        hipMemsetAsync(d_out, 0, (size_t)out_size * sizeof(float), stream);
        edge_scatter_kernel<<<(e_cg + 15) / 16, 256, 0, stream>>>(
            c_feat, cj_cell, mask_exp, ci_gene, src_cg, dst_cg, g_out, e_cg, 0.5f);
        edge_scatter_kernel<<<(e_gc + 15) / 16, 256, 0, stream>>>(
            g_feat, cj_gene, mask_rev, ci_cell, src_gc, dst_gc, c_out, e_gc, 1.0f);
        edge_scatter_kernel<<<(e_gg + 15) / 16, 256, 0, stream>>>(
            g_feat, cjj_gene, mask_gg, cii_gene, src_gg, dst_gg, g_out, e_gg, 0.5f);
        return;
    }

    // ---- build CSR per relation ----
    hipMemsetAsync(cnt_cg, 0, (size_t)(NG + NC + NG) * sizeof(int), stream);

    weights_kernel<<<(NC + 255) / 256, 256, 0, stream>>>(
        cj_cell, mask_exp, cj_gene, mask_rev, cjj_gene, mask_gg,
        w_cell, w_gene_rev, w_gene_gg);

    hist_lds_kernel<<<256, 256, 0, stream>>>(dst_cg, cnt_cg, e_cg);
    hist_lds_sliced_kernel<6250><<<8 * 20, 256, 0, stream>>>(dst_gc, cnt_gc, e_gc);
    hist_lds_kernel<<<64, 256, 0, stream>>>(dst_gg, cnt_gg, e_gg);

    scan3_kernel<<<3, 1024, 0, stream>>>(
        cnt_cg, off_cg, cur_cg, NG,
        cnt_gc, off_gc, cur_gc, NC,
        cnt_gg, off_gg, cur_gg, NG);

    // dst-sliced fills with nontemporal dst stream: DIV = ndst / 8
    fill_sliced_kernel<375><<<8 * 104, 256, 0, stream>>>(src_cg, dst_cg, cur_cg, bkt_cg, e_cg, e_cg);
    fill_sliced_kernel<6250><<<8 * 104, 256, 0, stream>>>(src_gc, dst_gc, cur_gc, bkt_gc, e_gc, e_gc);
    fill_kernel<<<256, 256, 0, stream>>>(src_gg, dst_gg, cur_gg, bkt_gg, e_gg, e_gg);

    // ---- gathers (write every output row -> no d_out memset needed) ----
    gather_kernel<false><<<(NG + 3) / 4, 256, 0, stream>>>(
        c_feat, w_cell, ci_gene, off_cg, bkt_cg, g_out, NG, e_cg, 0.5f);
    gather_kernel<false><<<(NC + 3) / 4, 256, 0, stream>>>(
        g_feat, w_gene_rev, ci_cell, off_gc, bkt_gc, c_out, NC, e_gc, 1.0f);
    gather_kernel<true><<<(NG + 3) / 4, 256, 0, stream>>>(
        g_feat, w_gene_gg, cii_gene, off_gg, bkt_gg, g_out, NG, e_gg, 0.5f);
}

// Round 6
// 526.405 us; speedup vs baseline: 2.5335x; 2.5335x over previous
//
#include <hip/hip_runtime.h>

#define NC 50000
#define NG 3000
#define D  64

// ======================= weights =======================

__global__ __launch_bounds__(256) void weights_kernel(
    const float* __restrict__ cj_cell, const float* __restrict__ mask_exp,
    const float* __restrict__ cj_gene, const float* __restrict__ mask_rev,
    const float* __restrict__ cjj_gene, const float* __restrict__ mask_gg,
    float* __restrict__ w_cell, float* __restrict__ w_gene_rev, float* __restrict__ w_gene_gg)
{
    int i = blockIdx.x * blockDim.x + threadIdx.x;
    if (i < NC) w_cell[i] = cj_cell[i] * mask_exp[i];
    if (i < NG) {
        w_gene_rev[i] = cj_gene[i] * mask_rev[i];
        w_gene_gg[i]  = cjj_gene[i] * mask_gg[i];
    }
}

// ======================= histograms =======================

// Bin-level histogram (bins = dst >> SHIFT), LDS-aggregated.
template <int SHIFT, int NBINS>
__global__ __launch_bounds__(256) void binhist_kernel(
    const int* __restrict__ dst, int* __restrict__ counts, int nedges)
{
    __shared__ int h[NBINS];
    for (int i = threadIdx.x; i < NBINS; i += 256) h[i] = 0;
    __syncthreads();
    for (long long e = (long long)blockIdx.x * 256 + threadIdx.x; e < nedges;
         e += (long long)gridDim.x * 256) {
        unsigned b = ((unsigned)dst[e]) >> SHIFT;
        if (b < (unsigned)NBINS) atomicAdd(&h[b], 1);
    }
    __syncthreads();
    for (int i = threadIdx.x; i < NBINS; i += 256) {
        int v = h[i];
        if (v) atomicAdd(&counts[i], v);
    }
}

// Full-range LDS histogram for the small gg relation (NG bins).
__global__ __launch_bounds__(256) void hist_lds_kernel(
    const int* __restrict__ dst, int* __restrict__ counts, int nedges)
{
    __shared__ int h[NG];
    for (int i = threadIdx.x; i < NG; i += 256) h[i] = 0;
    __syncthreads();
    for (long long e = (long long)blockIdx.x * 256 + threadIdx.x; e < nedges;
         e += (long long)gridDim.x * 256) {
        const int d = dst[e];
        if (d >= 0 && d < NG) atomicAdd(&h[d], 1);
    }
    __syncthreads();
    for (int i = threadIdx.x; i < NG; i += 256) {
        int v = h[i];
        if (v) atomicAdd(&counts[i], v);
    }
}

// ======================= scan (3 arrays, optional pad-to-16) =======================

__global__ __launch_bounds__(1024) void scan3_kernel(
    const int* __restrict__ c0, int* __restrict__ o0, int* __restrict__ u0, int n0, int p0,
    const int* __restrict__ c1, int* __restrict__ o1, int* __restrict__ u1, int n1, int p1,
    const int* __restrict__ c2, int* __restrict__ o2, int* __restrict__ u2, int n2, int p2)
{
    const int* counts; int* offs; int* cursor; int n; int pad;
    if (blockIdx.x == 0)      { counts = c0; offs = o0; cursor = u0; n = n0; pad = p0; }
    else if (blockIdx.x == 1) { counts = c1; offs = o1; cursor = u1; n = n1; pad = p1; }
    else                      { counts = c2; offs = o2; cursor = u2; n = n2; pad = p2; }

    __shared__ int wtot[16];
    __shared__ int woff[16];
    __shared__ int ctot_s;
    __shared__ int carry_s;
    const int tid  = threadIdx.x;
    const int lane = tid & 63;
    const int wid  = tid >> 6;
    if (tid == 0) carry_s = 0;
    __syncthreads();
    for (int base = 0; base < n; base += 1024) {
        int i = base + tid;
        int v = (i < n) ? counts[i] : 0;
        if (pad) v = (v + 15) & ~15;           // align each segment start to 64 B
        int incl = v;
        #pragma unroll
        for (int d = 1; d < 64; d <<= 1) {
            int t = __shfl_up(incl, d);
            if (lane >= d) incl += t;
        }
        if (lane == 63) wtot[wid] = incl;
        __syncthreads();
        if (wid == 0) {
            int t = (lane < 16) ? wtot[lane] : 0;
            #pragma unroll
            for (int d = 1; d < 16; d <<= 1) {
                int u = __shfl_up(t, d);
                if (lane >= d) t += u;
            }
            if (lane < 16) woff[lane] = t - wtot[lane];
            if (lane == 15) ctot_s = t;
        }
        __syncthreads();
        int excl = incl - v + woff[wid] + carry_s;
        if (i < n) { offs[i] = excl; cursor[i] = excl; }
        __syncthreads();
        if (tid == 0) carry_s += ctot_s;
        __syncthreads();
    }
    if (tid == 0) offs[n] = carry_s;
}

// ======================= partition (LDS write-combined bin sort) =======================
// Tiles of 8192 edges: LDS hist -> scan -> LDS scatter (sorted by bin) -> flush as
// contiguous per-bin runs via ONE global cursor atomic per (tile,bin).
// Packed u32 = bin<<PBITS | src<<SHIFT | dst_local.  Stored value = low PBITS bits.
template <int SHIFT, int NBINS, int PBITS>
__global__ __launch_bounds__(256) void partition_kernel(
    const int* __restrict__ src, const int* __restrict__ dst,
    int* __restrict__ chunk_cur, unsigned* __restrict__ bucket,
    int nedges, int bktcap)
{
    const int TILE = 8192;
    __shared__ int th[NBINS];
    __shared__ int toff[NBINS];
    __shared__ int tcur[NBINS];
    __shared__ int gb[NBINS];
    __shared__ unsigned staged[TILE];
    const int tid = threadIdx.x;
    const unsigned PMASK = (1u << PBITS) - 1u;

    for (long long tbase = (long long)blockIdx.x * TILE; tbase < nedges;
         tbase += (long long)gridDim.x * TILE) {
        const int n = (int)((nedges - tbase) < TILE ? (nedges - tbase) : TILE);
        for (int i = tid; i < NBINS; i += 256) { th[i] = 0; tcur[i] = 0; }
        __syncthreads();
        // pass 1: tile histogram over bins
        #pragma unroll 4
        for (int k = 0; k < 32; ++k) {
            int i = k * 256 + tid;
            if (i < n) {
                unsigned b = ((unsigned)dst[tbase + i]) >> SHIFT;
                if (b < (unsigned)NBINS) atomicAdd(&th[b], 1);
            }
        }
        __syncthreads();
        // wave-0 exclusive scan th -> toff
        if (tid < 64) {
            int carry = 0;
            for (int c = 0; c < NBINS; c += 64) {
                int idx = c + tid;
                int v = (idx < NBINS) ? th[idx] : 0;
                int incl = v;
                #pragma unroll
                for (int d = 1; d < 64; d <<= 1) {
                    int t = __shfl_up(incl, d);
                    if (tid >= d) incl += t;
                }
                if (idx < NBINS) toff[idx] = incl - v + carry;
                carry += __shfl(incl, 63);
            }
        }
        __syncthreads();
        // reserve global runs (one atomic per nonzero bin)
        for (int i = tid; i < NBINS; i += 256) {
            int c = th[i];
            if (c) gb[i] = atomicAdd(&chunk_cur[i], c);
        }
        __syncthreads();
        // pass 2: place packed edges into LDS, sorted by bin
        #pragma unroll 4
        for (int k = 0; k < 32; ++k) {
            int i = k * 256 + tid;
            if (i < n) {
                unsigned d = (unsigned)dst[tbase + i];
                unsigned s = (unsigned)src[tbase + i];
                unsigned b = d >> SHIFT;
                if (b < (unsigned)NBINS) {
                    int p = toff[b] + atomicAdd(&tcur[b], 1);
                    if (p >= 0 && p < TILE)
                        staged[p] = (b << PBITS) | (s << SHIFT) | (d & ((1u << SHIFT) - 1u));
                }
            }
        }
        __syncthreads();
        // flush: contiguous coalesced runs per bin
        for (int i = tid; i < n; i += 256) {
            unsigned v = staged[i];
            unsigned b = v >> PBITS;
            long long g = (long long)gb[b] + (i - toff[b]);
            if (g >= 0 && g < bktcap) bucket[g] = v & PMASK;
        }
        __syncthreads();
    }
}

// ======================= fused local-CSR + gather =======================
// One block per bin: sort the bin's packed edges by dst_local entirely in LDS,
// then gather rows with 4 feature-rows in flight per wave.
template <int SHIFT, int CAP>
__global__ __launch_bounds__(256) void csr_gather_kernel(
    const unsigned* __restrict__ bucket, const int* __restrict__ bin_cnt,
    const int* __restrict__ bin_off, const float* __restrict__ feat,
    const float* __restrict__ wsrc, const float* __restrict__ ci,
    float* __restrict__ out, int ndst, float alpha)
{
    const int DIV = 1 << SHIFT;
    __shared__ unsigned sorted[CAP];
    __shared__ int lh[DIV];
    __shared__ int loff[DIV];
    __shared__ int lcur[DIV];
    const int bin = blockIdx.x;
    const int n   = bin_cnt[bin];
    const long long base = bin_off[bin];
    const int tid  = threadIdx.x;
    const int lane = tid & 63;
    const int wid  = tid >> 6;
    const int grp  = lane >> 4;
    const int l16  = lane & 15;

    if (n <= CAP) {
        for (int i = tid; i < DIV; i += 256) { lh[i] = 0; lcur[i] = 0; }
        __syncthreads();
        for (int i = tid; i < n; i += 256)
            atomicAdd(&lh[bucket[base + i] & (DIV - 1)], 1);
        __syncthreads();
        if (tid < 64) {
            int carry = 0;
            for (int c = 0; c < DIV; c += 64) {
                int idx = c + tid;
                int v = (idx < DIV) ? lh[idx] : 0;
                int incl = v;
                #pragma unroll
                for (int d = 1; d < 64; d <<= 1) {
                    int t = __shfl_up(incl, d);
                    if (tid >= d) incl += t;
                }
                if (idx < DIV) loff[idx] = incl - v + carry;
                carry += __shfl(incl, 63);
            }
        }
        __syncthreads();
        for (int i = tid; i < n; i += 256) {
            unsigned v = bucket[base + i];
            int d = v & (DIV - 1);
            int p = loff[d] + atomicAdd(&lcur[d], 1);
            if (p >= 0 && p < CAP) sorted[p] = v;
        }
        __syncthreads();
        for (int cell = wid; cell < DIV; cell += 4) {
            const int r = (bin << SHIFT) + cell;
            if (r >= ndst) continue;
            const int lo = loff[cell];
            const int hi = lo + lh[cell];
            float4 acc = make_float4(0.f, 0.f, 0.f, 0.f);
            for (int jj = lo; jj < hi; jj += 4) {
                const int j = jj + grp;
                const bool valid = (j < hi);
                const unsigned v = valid ? sorted[j] : 0u;
                const int s = v >> SHIFT;
                const float w = valid ? wsrc[s] : 0.0f;
                const float4 f = *(const float4*)(feat + (size_t)s * D + l16 * 4);
                acc.x += w * f.x; acc.y += w * f.y; acc.z += w * f.z; acc.w += w * f.w;
            }
            #pragma unroll
            for (int off = 16; off < 64; off <<= 1) {
                acc.x += __shfl_xor(acc.x, off);
                acc.y += __shfl_xor(acc.y, off);
                acc.z += __shfl_xor(acc.z, off);
                acc.w += __shfl_xor(acc.w, off);
            }
            if (grp == 0) {
                const float sci = ci[r] * alpha;
                float* o = out + (size_t)r * D + l16 * 4;
                *(float4*)o = make_float4(acc.x * sci, acc.y * sci, acc.z * sci, acc.w * sci);
            }
        }
    } else {
        // statistically-unreachable slow path (bin overflow): O(DIV*n) but correct
        for (int cell = wid; cell < DIV; cell += 4) {
            const int r = (bin << SHIFT) + cell;
            if (r >= ndst) continue;
            float4 acc = make_float4(0.f, 0.f, 0.f, 0.f);
            for (int jj = 0; jj < n; jj += 4) {
                const int j = jj + grp;
                const bool valid = (j < n);
                const unsigned v = valid ? bucket[base + j] : 0u;
                const bool ok = valid && ((int)(v & (DIV - 1)) == cell);
                const int s = v >> SHIFT;
                const float w = ok ? wsrc[s] : 0.0f;
                const float4 f = *(const float4*)(feat + (size_t)s * D + l16 * 4);
                acc.x += w * f.x; acc.y += w * f.y; acc.z += w * f.z; acc.w += w * f.w;
            }
            #pragma unroll
            for (int off = 16; off < 64; off <<= 1) {
                acc.x += __shfl_xor(acc.x, off);
                acc.y += __shfl_xor(acc.y, off);
                acc.z += __shfl_xor(acc.z, off);
                acc.w += __shfl_xor(acc.w, off);
            }
            if (grp == 0) {
                const float sci = ci[r] * alpha;
                float* o = out + (size_t)r * D + l16 * 4;
                *(float4*)o = make_float4(acc.x * sci, acc.y * sci, acc.z * sci, acc.w * sci);
            }
        }
    }
}

// ======================= small gg path (proven) =======================

__global__ __launch_bounds__(256) void fill_kernel(
    const int* __restrict__ src, const int* __restrict__ dst,
    int* __restrict__ cursor, int* __restrict__ bucket, int nedges, int ntot)
{
    for (long long e = (long long)blockIdx.x * 256 + threadIdx.x; e < nedges;
         e += (long long)gridDim.x * 256) {
        int pos = atomicAdd(&cursor[dst[e]], 1);
        if (pos >= 0 && pos < ntot) bucket[pos] = src[e];
    }
}

template <bool ACC>
__global__ __launch_bounds__(256) void gather_kernel(
    const float* __restrict__ feat, const float* __restrict__ wsrc,
    const float* __restrict__ ci, const int* __restrict__ offs,
    const int* __restrict__ bucket, float* __restrict__ out, int ndst, int ntot,
    float alpha)
{
    const int row = blockIdx.x * 4 + (threadIdx.x >> 6);
    if (row >= ndst) return;
    const int lane = threadIdx.x & 63;
    const int grp  = lane >> 4;
    const int l16  = lane & 15;
    int begin = offs[row], end = offs[row + 1];
    begin = begin < 0 ? 0 : (begin > ntot ? ntot : begin);
    end   = end   < 0 ? 0 : (end   > ntot ? ntot : end);

    float4 acc = make_float4(0.f, 0.f, 0.f, 0.f);
    for (int jj = begin; jj < end; jj += 4) {
        const int  j     = jj + grp;
        const bool valid = (j < end);
        const int  s     = valid ? bucket[j] : 0;
        const float w    = valid ? wsrc[s] : 0.0f;
        const float4 v = *(const float4*)(feat + (size_t)s * D + l16 * 4);
        acc.x += w * v.x; acc.y += w * v.y; acc.z += w * v.z; acc.w += w * v.w;
    }
    #pragma unroll
    for (int off = 16; off < 64; off <<= 1) {
        acc.x += __shfl_xor(acc.x, off);
        acc.y += __shfl_xor(acc.y, off);
        acc.z += __shfl_xor(acc.z, off);
        acc.w += __shfl_xor(acc.w, off);
    }
    if (grp == 0) {
        const float s_ci = ci[row] * alpha;
        float* o = out + (size_t)row * D + l16 * 4;
        float4 r = make_float4(acc.x * s_ci, acc.y * s_ci, acc.z * s_ci, acc.w * s_ci);
        if (ACC) {
            const float4 prev = *(const float4*)o;
            r.x += prev.x; r.y += prev.y; r.z += prev.z; r.w += prev.w;
        }
        *(float4*)o = r;
    }
}

// ======================= fallback (atomic scatter) =======================

__global__ __launch_bounds__(256) void edge_scatter_kernel(
    const float* __restrict__ feat, const float* __restrict__ cj,
    const float* __restrict__ mask, const float* __restrict__ ci,
    const int* __restrict__ src, const int* __restrict__ dst,
    float* __restrict__ out, int nedges, float alpha)
{
    const int lane16 = threadIdx.x & 15;
    const int eloc   = threadIdx.x >> 4;
    const long long e = (long long)blockIdx.x * 16 + eloc;
    if (e >= nedges) return;
    const int s = src[e];
    const int t = dst[e];
    const float w = cj[s] * mask[s] * ci[t] * alpha;
    const float4 v = *(const float4*)(feat + (size_t)s * D + lane16 * 4);
    float* o = out + (size_t)t * D + lane16 * 4;
#if defined(__HIP_DEVICE_COMPILE__)
    unsafeAtomicAdd(o + 0, w * v.x);
    unsafeAtomicAdd(o + 1, w * v.y);
    unsafeAtomicAdd(o + 2, w * v.z);
    unsafeAtomicAdd(o + 3, w * v.w);
#endif
}

// ======================= launch =======================

// cg: bins of 4 genes  -> SHIFT=2, NBINS=750, PBITS=18 (src 16b | dloc 2b), CAP 6144
// gc: bins of 64 cells -> SHIFT=6, NBINS=782, PBITS=18 (src 12b | dloc 6b), CAP 5120
#define NB_CG 750
#define NB_GC 782

extern "C" void kernel_launch(void* const* d_in, const int* in_sizes, int n_in,
                              void* d_out, int out_size, void* d_ws, size_t ws_size,
                              hipStream_t stream)
{
    const float* c_feat   = (const float*)d_in[0];
    const float* g_feat   = (const float*)d_in[1];
    const float* cj_cell  = (const float*)d_in[2];
    const float* ci_cell  = (const float*)d_in[3];
    const float* cj_gene  = (const float*)d_in[4];
    const float* ci_gene  = (const float*)d_in[5];
    const float* cjj_gene = (const float*)d_in[6];
    const float* cii_gene = (const float*)d_in[7];
    const float* mask_exp = (const float*)d_in[8];
    const float* mask_rev = (const float*)d_in[9];
    const float* mask_gg  = (const float*)d_in[10];
    const int*   src_cg   = (const int*)d_in[11];
    const int*   dst_cg   = (const int*)d_in[12];
    const int*   src_gc   = (const int*)d_in[13];
    const int*   dst_gc   = (const int*)d_in[14];
    const int*   src_gg   = (const int*)d_in[15];
    const int*   dst_gg   = (const int*)d_in[16];

    const int e_cg = in_sizes[11];
    const int e_gc = in_sizes[13];
    const int e_gg = in_sizes[15];

    float* c_out = (float*)d_out;                   // [NC, D]
    float* g_out = (float*)d_out + (size_t)NC * D;  // [NG, D]

    const int cap_cg = e_cg + 16 * NB_CG;
    const int cap_gc = e_gc + 16 * NB_GC;

    // ---- workspace layout (int units) ----
    int* ws = (int*)d_ws;
    size_t p = 0;
    int* cntb_cg = ws + p; p += NB_CG;
    int* cntb_gc = ws + p; p += NB_GC;
    int* cnt_gg  = ws + p; p += NG;        // counts contiguous -> one memset
    int* offb_cg = ws + p; p += NB_CG + 1;
    int* offb_gc = ws + p; p += NB_GC + 1;
    int* off_gg  = ws + p; p += NG + 1;
    int* curb_cg = ws + p; p += NB_CG;
    int* curb_gc = ws + p; p += NB_GC;
    int* cur_gg  = ws + p; p += NG;
    float* w_cell     = (float*)(ws + p); p += NC;
    float* w_gene_rev = (float*)(ws + p); p += NG;
    float* w_gene_gg  = (float*)(ws + p); p += NG;
    unsigned* ubkt_cg = (unsigned*)(ws + p); p += cap_cg;
    unsigned* ubkt_gc = (unsigned*)(ws + p); p += cap_gc;
    int* bkt_gg = ws + p; p += e_gg;
    const size_t need = p * sizeof(int);

    if (need > ws_size) {
        hipMemsetAsync(d_out, 0, (size_t)out_size * sizeof(float), stream);
        edge_scatter_kernel<<<(e_cg + 15) / 16, 256, 0, stream>>>(
            c_feat, cj_cell, mask_exp, ci_gene, src_cg, dst_cg, g_out, e_cg, 0.5f);
        edge_scatter_kernel<<<(e_gc + 15) / 16, 256, 0, stream>>>(
            g_feat, cj_gene, mask_rev, ci_cell, src_gc, dst_gc, c_out, e_gc, 1.0f);
        edge_scatter_kernel<<<(e_gg + 15) / 16, 256, 0, stream>>>(
            g_feat, cjj_gene, mask_gg, cii_gene, src_gg, dst_gg, g_out, e_gg, 0.5f);
        return;
    }

    hipMemsetAsync(cntb_cg, 0, (size_t)(NB_CG + NB_GC + NG) * sizeof(int), stream);

    weights_kernel<<<(NC + 255) / 256, 256, 0, stream>>>(
        cj_cell, mask_exp, cj_gene, mask_rev, cjj_gene, mask_gg,
        w_cell, w_gene_rev, w_gene_gg);

    binhist_kernel<2, NB_CG><<<256, 256, 0, stream>>>(dst_cg, cntb_cg, e_cg);
    binhist_kernel<6, NB_GC><<<256, 256, 0, stream>>>(dst_gc, cntb_gc, e_gc);
    hist_lds_kernel<<<64, 256, 0, stream>>>(dst_gg, cnt_gg, e_gg);

    scan3_kernel<<<3, 1024, 0, stream>>>(
        cntb_cg, offb_cg, curb_cg, NB_CG, 1,
        cntb_gc, offb_gc, curb_gc, NB_GC, 1,
        cnt_gg,  off_gg,  cur_gg,  NG,    0);

    partition_kernel<2, NB_CG, 18><<<256, 256, 0, stream>>>(
        src_cg, dst_cg, curb_cg, ubkt_cg, e_cg, cap_cg);
    partition_kernel<6, NB_GC, 18><<<256, 256, 0, stream>>>(
        src_gc, dst_gc, curb_gc, ubkt_gc, e_gc, cap_gc);
    fill_kernel<<<256, 256, 0, stream>>>(src_gg, dst_gg, cur_gg, bkt_gg, e_gg, e_gg);

    // fused local-CSR + gather; every output row written exactly once -> no d_out memset
    csr_gather_kernel<2, 6144><<<NB_CG, 256, 0, stream>>>(
        ubkt_cg, cntb_cg, offb_cg, c_feat, w_cell, ci_gene, g_out, NG, 0.5f);
    csr_gather_kernel<6, 5120><<<NB_GC, 256, 0, stream>>>(
        ubkt_gc, cntb_gc, offb_gc, g_feat, w_gene_rev, ci_cell, c_out, NC, 1.0f);
    gather_kernel<true><<<(NG + 3) / 4, 256, 0, stream>>>(
        g_feat, w_gene_gg, cii_gene, off_gg, bkt_gg, g_out, NG, e_gg, 0.5f);
}

// Round 7
// 372.660 us; speedup vs baseline: 3.5788x; 1.4126x over previous
//
#include <hip/hip_runtime.h>

#define NC 50000
#define NG 3000
#define D  64

#define NB_CG 750   // gene bins of 4   (SHIFT 2), 750*4  = 3000
#define NB_GC 782   // cell bins of 64  (SHIFT 6), 782*64 = 50048
#define PBITS 18
#define TILE  8192

__device__ inline unsigned short f2bf(float x) {
    unsigned u = __float_as_uint(x);
    unsigned r = u + 0x7FFFu + ((u >> 16) & 1u);
    return (unsigned short)(r >> 16);
}
__device__ inline float bf2f(unsigned short h) {
    return __uint_as_float(((unsigned)h) << 16);
}

// 16-lane row fragment loader: lane l16 reads elems [4*l16, 4*l16+4) of row s.
template <bool BF16>
__device__ inline float4 row16(const void* feat, int s, int l16) {
    if (BF16) {
        const ushort4 q = ((const ushort4*)((const unsigned short*)feat + (size_t)s * D))[l16];
        return make_float4(bf2f(q.x), bf2f(q.y), bf2f(q.z), bf2f(q.w));
    } else {
        return ((const float4*)((const float*)feat + (size_t)s * D))[l16];
    }
}

// ======================= prep: weights + optional bf16 feature conversion =======================

__global__ __launch_bounds__(256) void prep_kernel(
    const float* __restrict__ cj_cell, const float* __restrict__ mask_exp,
    const float* __restrict__ cj_gene, const float* __restrict__ mask_rev,
    const float* __restrict__ cjj_gene, const float* __restrict__ mask_gg,
    float* __restrict__ w_cell, float* __restrict__ w_rev, float* __restrict__ w_gg,
    const float* __restrict__ c_feat, const float* __restrict__ g_feat,
    unsigned short* __restrict__ cf16, unsigned short* __restrict__ gf16, int do_cvt)
{
    const int i = blockIdx.x * 256 + threadIdx.x;
    if (i < NC) w_cell[i] = cj_cell[i] * mask_exp[i];
    if (i < NG) {
        w_rev[i] = cj_gene[i] * mask_rev[i];
        w_gg[i]  = cjj_gene[i] * mask_gg[i];
    }
    if (do_cvt) {
        const long long total8 = (long long)(NC + NG) * D / 8;
        for (long long t = (long long)blockIdx.x * 256 + threadIdx.x; t < total8;
             t += (long long)gridDim.x * 256) {
            const long long base = t * 8;
            const float* sp; unsigned short* dp;
            if (base < (long long)NC * D) { sp = c_feat + base; dp = cf16 + base; }
            else { sp = g_feat + (base - (long long)NC * D); dp = gf16 + (base - (long long)NC * D); }
            const float4 a = ((const float4*)sp)[0];
            const float4 b = ((const float4*)sp)[1];
            ushort4 o0 = make_ushort4(f2bf(a.x), f2bf(a.y), f2bf(a.z), f2bf(a.w));
            ushort4 o1 = make_ushort4(f2bf(b.x), f2bf(b.y), f2bf(b.z), f2bf(b.w));
            ((ushort4*)dp)[0] = o0;
            ((ushort4*)dp)[1] = o1;
        }
    }
}

// ======================= fused histograms (cg bins | gc bins | gg full) =======================

__global__ __launch_bounds__(256) void hist3_kernel(
    const int* __restrict__ dst_cg, int e_cg, int* __restrict__ cnt_cg,
    const int* __restrict__ dst_gc, int e_gc, int* __restrict__ cnt_gc,
    const int* __restrict__ dst_gg, int e_gg, int* __restrict__ cnt_gg)
{
    __shared__ int h[NG];   // 12 KB, max of all segments
    const int* dst; int* cnt; int ne, nbins, shift, bid, nblk;
    if (blockIdx.x < 256)      { dst = dst_cg; cnt = cnt_cg; ne = e_cg; nbins = NB_CG; shift = 2; bid = blockIdx.x;       nblk = 256; }
    else if (blockIdx.x < 512) { dst = dst_gc; cnt = cnt_gc; ne = e_gc; nbins = NB_GC; shift = 6; bid = blockIdx.x - 256; nblk = 256; }
    else                       { dst = dst_gg; cnt = cnt_gg; ne = e_gg; nbins = NG;    shift = 0; bid = blockIdx.x - 512; nblk = 64;  }
    const int tid = threadIdx.x;
    for (int i = tid; i < nbins; i += 256) h[i] = 0;
    __syncthreads();
    for (long long e = (long long)bid * 256 + tid; e < ne; e += (long long)nblk * 256) {
        unsigned b = ((unsigned)dst[e]) >> shift;
        if (b < (unsigned)nbins) atomicAdd(&h[b], 1);
    }
    __syncthreads();
    for (int i = tid; i < nbins; i += 256) {
        int v = h[i];
        if (v) atomicAdd(&cnt[i], v);
    }
}

// ======================= scan (3 arrays, optional pad-to-16) =======================

__global__ __launch_bounds__(1024) void scan3_kernel(
    const int* __restrict__ c0, int* __restrict__ o0, int* __restrict__ u0, int n0, int p0,
    const int* __restrict__ c1, int* __restrict__ o1, int* __restrict__ u1, int n1, int p1,
    const int* __restrict__ c2, int* __restrict__ o2, int* __restrict__ u2, int n2, int p2)
{
    const int* counts; int* offs; int* cursor; int n; int pad;
    if (blockIdx.x == 0)      { counts = c0; offs = o0; cursor = u0; n = n0; pad = p0; }
    else if (blockIdx.x == 1) { counts = c1; offs = o1; cursor = u1; n = n1; pad = p1; }
    else                      { counts = c2; offs = o2; cursor = u2; n = n2; pad = p2; }

    __shared__ int wtot[16];
    __shared__ int woff[16];
    __shared__ int ctot_s;
    __shared__ int carry_s;
    const int tid  = threadIdx.x;
    const int lane = tid & 63;
    const int wid  = tid >> 6;
    if (tid == 0) carry_s = 0;
    __syncthreads();
    for (int base = 0; base < n; base += 1024) {
        int i = base + tid;
        int v = (i < n) ? counts[i] : 0;
        if (pad) v = (v + 15) & ~15;
        int incl = v;
        #pragma unroll
        for (int d = 1; d < 64; d <<= 1) {
            int t = __shfl_up(incl, d);
            if (lane >= d) incl += t;
        }
        if (lane == 63) wtot[wid] = incl;
        __syncthreads();
        if (wid == 0) {
            int t = (lane < 16) ? wtot[lane] : 0;
            #pragma unroll
            for (int d = 1; d < 16; d <<= 1) {
                int u = __shfl_up(t, d);
                if (lane >= d) t += u;
            }
            if (lane < 16) woff[lane] = t - wtot[lane];
            if (lane == 15) ctot_s = t;
        }
        __syncthreads();
        int excl = incl - v + woff[wid] + carry_s;
        if (i < n) { offs[i] = excl; cursor[i] = excl; }
        __syncthreads();
        if (tid == 0) carry_s += ctot_s;
        __syncthreads();
    }
    if (tid == 0) offs[n] = carry_s;
}

// ======================= fused partition (cg | gc) + gg fill =======================
// Partition: tiles of 8192 edges, LDS bin-sort, flush contiguous runs
// (one global cursor atomic per tile×bin). Packed u32 = bin<<18 | src<<shift | dloc.
__global__ __launch_bounds__(256) void part3_kernel(
    const int* __restrict__ src_cg, const int* __restrict__ dst_cg, int e_cg,
    int* __restrict__ cur_cg, unsigned* __restrict__ ubkt_cg, int cap_cg,
    const int* __restrict__ src_gc, const int* __restrict__ dst_gc, int e_gc,
    int* __restrict__ cur_gc, unsigned* __restrict__ ubkt_gc, int cap_gc,
    const int* __restrict__ src_gg, const int* __restrict__ dst_gg, int e_gg,
    int* __restrict__ cur_gg, int* __restrict__ bkt_gg)
{
    const int tid = threadIdx.x;
    if (blockIdx.x >= 512) {   // gg fill (64 blocks)
        for (long long e = (long long)(blockIdx.x - 512) * 256 + tid; e < e_gg;
             e += (long long)64 * 256) {
            int pos = atomicAdd(&cur_gg[dst_gg[e]], 1);
            if (pos >= 0 && pos < e_gg) bkt_gg[pos] = src_gg[e];
        }
        return;
    }
    const int* src; const int* dst; int ne; int* ccur; unsigned* bkt; int cap, shift, nbins, bid;
    if (blockIdx.x < 256) { src = src_cg; dst = dst_cg; ne = e_cg; ccur = cur_cg; bkt = ubkt_cg; cap = cap_cg; shift = 2; nbins = NB_CG; bid = blockIdx.x; }
    else                  { src = src_gc; dst = dst_gc; ne = e_gc; ccur = cur_gc; bkt = ubkt_gc; cap = cap_gc; shift = 6; nbins = NB_GC; bid = blockIdx.x - 256; }

    __shared__ int th[784];
    __shared__ int toff[784];
    __shared__ int tcur[784];
    __shared__ int gb[784];
    __shared__ unsigned staged[TILE];
    const unsigned PMASK = (1u << PBITS) - 1u;
    const unsigned DMASK = (1u << shift) - 1u;

    for (long long tbase = (long long)bid * TILE; tbase < ne;
         tbase += (long long)256 * TILE) {
        const int n = (int)((ne - tbase) < TILE ? (ne - tbase) : TILE);
        for (int i = tid; i < nbins; i += 256) { th[i] = 0; tcur[i] = 0; }
        __syncthreads();
        #pragma unroll 4
        for (int k = 0; k < 32; ++k) {
            int i = k * 256 + tid;
            if (i < n) {
                unsigned b = ((unsigned)dst[tbase + i]) >> shift;
                if (b < (unsigned)nbins) atomicAdd(&th[b], 1);
            }
        }
        __syncthreads();
        if (tid < 64) {
            int carry = 0;
            for (int c = 0; c < nbins; c += 64) {
                int idx = c + tid;
                int v = (idx < nbins) ? th[idx] : 0;
                int incl = v;
                #pragma unroll
                for (int d = 1; d < 64; d <<= 1) {
                    int t = __shfl_up(incl, d);
                    if (tid >= d) incl += t;
                }
                if (idx < nbins) toff[idx] = incl - v + carry;
                carry += __shfl(incl, 63);
            }
        }
        __syncthreads();
        for (int i = tid; i < nbins; i += 256) {
            int c = th[i];
            if (c) gb[i] = atomicAdd(&ccur[i], c);
        }
        __syncthreads();
        #pragma unroll 4
        for (int k = 0; k < 32; ++k) {
            int i = k * 256 + tid;
            if (i < n) {
                unsigned d = (unsigned)dst[tbase + i];
                unsigned s = (unsigned)src[tbase + i];
                unsigned b = d >> shift;
                if (b < (unsigned)nbins) {
                    int p = toff[b] + atomicAdd(&tcur[b], 1);
                    if (p >= 0 && p < TILE)
                        staged[p] = (b << PBITS) | (s << shift) | (d & DMASK);
                }
            }
        }
        __syncthreads();
        for (int i = tid; i < n; i += 256) {
            unsigned v = staged[i];
            unsigned b = v >> PBITS;
            long long g = (long long)gb[b] + (i - toff[b]);
            if (g >= 0 && g < cap) bkt[g] = v & PMASK;
        }
        __syncthreads();
    }
}

// ======================= fused gather (cg bins + gg fold-in | gc bins) =======================
// One block per bin: LDS counting-sort by dst_local, then per-cell gather with
// 4 feature-rows in flight per wave. Gene bins also fold in the gg relation so
// g_out is written exactly once.
template <bool BF16>
__global__ __launch_bounds__(256) void gather3_kernel(
    const unsigned* __restrict__ ubkt_cg, const int* __restrict__ cntb_cg, const int* __restrict__ offb_cg,
    const unsigned* __restrict__ ubkt_gc, const int* __restrict__ cntb_gc, const int* __restrict__ offb_gc,
    const void* __restrict__ cfeat, const void* __restrict__ gfeat,
    const float* __restrict__ w_cell, const float* __restrict__ w_rev, const float* __restrict__ w_gg,
    const float* __restrict__ ci_gene, const float* __restrict__ cii_gene, const float* __restrict__ ci_cell,
    const int* __restrict__ off_gg, const int* __restrict__ bkt_gg, int e_gg,
    float* __restrict__ g_out, float* __restrict__ c_out)
{
    const int CAPV = 6144;
    __shared__ unsigned sorted[6144];
    __shared__ int lh[64];
    __shared__ int loff[64];
    __shared__ int lcur[64];

    const bool is_cg = (blockIdx.x < NB_CG);
    const int bin = is_cg ? blockIdx.x : blockIdx.x - NB_CG;
    const int n = (is_cg ? cntb_cg : cntb_gc)[bin];
    const long long base = (is_cg ? offb_cg : offb_gc)[bin];
    const unsigned* bkt = is_cg ? ubkt_cg : ubkt_gc;
    const void* feat = is_cg ? cfeat : gfeat;
    const float* wsrc = is_cg ? w_cell : w_rev;
    const int shift = is_cg ? 2 : 6;
    const int DIVv = 1 << shift;
    const int tid  = threadIdx.x;
    const int lane = tid & 63;
    const int wid  = tid >> 6;
    const int grp  = lane >> 4;
    const int l16  = lane & 15;
    const bool fast = (n <= CAPV);

    if (fast) {
        for (int i = tid; i < DIVv; i += 256) { lh[i] = 0; lcur[i] = 0; }
        __syncthreads();
        for (int i = tid; i < n; i += 256)
            atomicAdd(&lh[bkt[base + i] & (DIVv - 1)], 1);
        __syncthreads();
        if (tid < 64) {
            int v = (tid < DIVv) ? lh[tid] : 0;
            int incl = v;
            #pragma unroll
            for (int d = 1; d < 64; d <<= 1) {
                int t = __shfl_up(incl, d);
                if (tid >= d) incl += t;
            }
            if (tid < DIVv) loff[tid] = incl - v;
        }
        __syncthreads();
        for (int i = tid; i < n; i += 256) {
            unsigned v = bkt[base + i];
            int d = v & (DIVv - 1);
            int p = loff[d] + atomicAdd(&lcur[d], 1);
            if (p >= 0 && p < CAPV) sorted[p] = v;
        }
        __syncthreads();
    }

    for (int cell = wid; cell < DIVv; cell += 4) {
        const int r = (bin << shift) + cell;
        if (is_cg) { if (r >= NG) continue; } else { if (r >= NC) continue; }

        float4 accA = make_float4(0.f, 0.f, 0.f, 0.f);
        if (fast) {
            const int lo = loff[cell], hi = loff[cell] + lh[cell];
            for (int jj = lo; jj < hi; jj += 4) {
                const int j = jj + grp;
                const bool valid = (j < hi);
                const unsigned v = valid ? sorted[j] : 0u;
                const int s = v >> shift;
                const float w = valid ? wsrc[s] : 0.0f;
                const float4 f = row16<BF16>(feat, s, l16);
                accA.x += w * f.x; accA.y += w * f.y; accA.z += w * f.z; accA.w += w * f.w;
            }
        } else {
            for (int jj = 0; jj < n; jj += 4) {
                const int j = jj + grp;
                const bool valid = (j < n);
                const unsigned v = valid ? bkt[base + j] : 0u;
                const bool ok = valid && ((int)(v & (DIVv - 1)) == cell);
                const int s = v >> shift;
                const float w = ok ? wsrc[s] : 0.0f;
                const float4 f = row16<BF16>(feat, s, l16);
                accA.x += w * f.x; accA.y += w * f.y; accA.z += w * f.z; accA.w += w * f.w;
            }
        }

        float4 accB = make_float4(0.f, 0.f, 0.f, 0.f);
        if (is_cg) {
            int lo = off_gg[r], hi = off_gg[r + 1];
            lo = lo < 0 ? 0 : (lo > e_gg ? e_gg : lo);
            hi = hi < 0 ? 0 : (hi > e_gg ? e_gg : hi);
            for (int jj = lo; jj < hi; jj += 4) {
                const int j = jj + grp;
                const bool valid = (j < hi);
                const int s = valid ? bkt_gg[j] : 0;
                const float w = valid ? w_gg[s] : 0.0f;
                const float4 f = row16<BF16>(gfeat, s, l16);
                accB.x += w * f.x; accB.y += w * f.y; accB.z += w * f.z; accB.w += w * f.w;
            }
        }

        #pragma unroll
        for (int off = 16; off < 64; off <<= 1) {
            accA.x += __shfl_xor(accA.x, off);
            accA.y += __shfl_xor(accA.y, off);
            accA.z += __shfl_xor(accA.z, off);
            accA.w += __shfl_xor(accA.w, off);
        }
        if (is_cg) {
            #pragma unroll
            for (int off = 16; off < 64; off <<= 1) {
                accB.x += __shfl_xor(accB.x, off);
                accB.y += __shfl_xor(accB.y, off);
                accB.z += __shfl_xor(accB.z, off);
                accB.w += __shfl_xor(accB.w, off);
            }
        }
        if (grp == 0) {
            if (is_cg) {
                const float sa = 0.5f * ci_gene[r];
                const float sb = 0.5f * cii_gene[r];
                float* o = g_out + (size_t)r * D + l16 * 4;
                *(float4*)o = make_float4(sa * accA.x + sb * accB.x,
                                          sa * accA.y + sb * accB.y,
                                          sa * accA.z + sb * accB.z,
                                          sa * accA.w + sb * accB.w);
            } else {
                const float sc = ci_cell[r];
                float* o = c_out + (size_t)r * D + l16 * 4;
                *(float4*)o = make_float4(sc * accA.x, sc * accA.y, sc * accA.z, sc * accA.w);
            }
        }
    }
}

// ======================= fallback (atomic scatter) =======================

__global__ __launch_bounds__(256) void edge_scatter_kernel(
    const float* __restrict__ feat, const float* __restrict__ cj,
    const float* __restrict__ mask, const float* __restrict__ ci,
    const int* __restrict__ src, const int* __restrict__ dst,
    float* __restrict__ out, int nedges, float alpha)
{
    const int lane16 = threadIdx.x & 15;
    const int eloc   = threadIdx.x >> 4;
    const long long e = (long long)blockIdx.x * 16 + eloc;
    if (e >= nedges) return;
    const int s = src[e];
    const int t = dst[e];
    const float w = cj[s] * mask[s] * ci[t] * alpha;
    const float4 v = *(const float4*)(feat + (size_t)s * D + lane16 * 4);
    float* o = out + (size_t)t * D + lane16 * 4;
#if defined(__HIP_DEVICE_COMPILE__)
    unsafeAtomicAdd(o + 0, w * v.x);
    unsafeAtomicAdd(o + 1, w * v.y);
    unsafeAtomicAdd(o + 2, w * v.z);
    unsafeAtomicAdd(o + 3, w * v.w);
#endif
}

// ======================= launch =======================

extern "C" void kernel_launch(void* const* d_in, const int* in_sizes, int n_in,
                              void* d_out, int out_size, void* d_ws, size_t ws_size,
                              hipStream_t stream)
{
    const float* c_feat   = (const float*)d_in[0];
    const float* g_feat   = (const float*)d_in[1];
    const float* cj_cell  = (const float*)d_in[2];
    const float* ci_cell  = (const float*)d_in[3];
    const float* cj_gene  = (const float*)d_in[4];
    const float* ci_gene  = (const float*)d_in[5];
    const float* cjj_gene = (const float*)d_in[6];
    const float* cii_gene = (const float*)d_in[7];
    const float* mask_exp = (const float*)d_in[8];
    const float* mask_rev = (const float*)d_in[9];
    const float* mask_gg  = (const float*)d_in[10];
    const int*   src_cg   = (const int*)d_in[11];
    const int*   dst_cg   = (const int*)d_in[12];
    const int*   src_gc   = (const int*)d_in[13];
    const int*   dst_gc   = (const int*)d_in[14];
    const int*   src_gg   = (const int*)d_in[15];
    const int*   dst_gg   = (const int*)d_in[16];

    const int e_cg = in_sizes[11];
    const int e_gc = in_sizes[13];
    const int e_gg = in_sizes[15];

    float* c_out = (float*)d_out;                   // [NC, D]
    float* g_out = (float*)d_out + (size_t)NC * D;  // [NG, D]

    const int cap_cg = e_cg + 16 * NB_CG;
    const int cap_gc = e_gc + 16 * NB_GC;

    // ---- workspace layout (int units) ----
    int* ws = (int*)d_ws;
    size_t p = 0;
    int* cntb_cg = ws + p; p += NB_CG;
    int* cntb_gc = ws + p; p += NB_GC;
    int* cnt_gg  = ws + p; p += NG;        // counts contiguous -> one memset
    int* offb_cg = ws + p; p += NB_CG + 1;
    int* offb_gc = ws + p; p += NB_GC + 1;
    int* off_gg  = ws + p; p += NG + 1;
    int* curb_cg = ws + p; p += NB_CG;
    int* curb_gc = ws + p; p += NB_GC;
    int* cur_gg  = ws + p; p += NG;
    float* w_cell = (float*)(ws + p); p += NC;
    float* w_rev  = (float*)(ws + p); p += NG;
    float* w_gg   = (float*)(ws + p); p += NG;
    unsigned* ubkt_cg = (unsigned*)(ws + p); p += cap_cg;
    unsigned* ubkt_gc = (unsigned*)(ws + p); p += cap_gc;
    int* bkt_gg = ws + p; p += e_gg;
    const size_t need_base = p * sizeof(int);
    unsigned short* cf16 = (unsigned short*)(ws + p); p += (size_t)NC * D / 2;
    unsigned short* gf16 = (unsigned short*)(ws + p); p += (size_t)NG * D / 2;
    const size_t need_full = p * sizeof(int);

    if (need_base > ws_size) {
        hipMemsetAsync(d_out, 0, (size_t)out_size * sizeof(float), stream);
        edge_scatter_kernel<<<(e_cg + 15) / 16, 256, 0, stream>>>(
            c_feat, cj_cell, mask_exp, ci_gene, src_cg, dst_cg, g_out, e_cg, 0.5f);
        edge_scatter_kernel<<<(e_gc + 15) / 16, 256, 0, stream>>>(
            g_feat, cj_gene, mask_rev, ci_cell, src_gc, dst_gc, c_out, e_gc, 1.0f);
        edge_scatter_kernel<<<(e_gg + 15) / 16, 256, 0, stream>>>(
            g_feat, cjj_gene, mask_gg, cii_gene, src_gg, dst_gg, g_out, e_gg, 0.5f);
        return;
    }
    const int use_bf16 = (need_full <= ws_size) ? 1 : 0;

    hipMemsetAsync(cntb_cg, 0, (size_t)(NB_CG + NB_GC + NG) * sizeof(int), stream);

    prep_kernel<<<1657, 256, 0, stream>>>(
        cj_cell, mask_exp, cj_gene, mask_rev, cjj_gene, mask_gg,
        w_cell, w_rev, w_gg, c_feat, g_feat, cf16, gf16, use_bf16);

    hist3_kernel<<<576, 256, 0, stream>>>(
        dst_cg, e_cg, cntb_cg, dst_gc, e_gc, cntb_gc, dst_gg, e_gg, cnt_gg);

    scan3_kernel<<<3, 1024, 0, stream>>>(
        cntb_cg, offb_cg, curb_cg, NB_CG, 1,
        cntb_gc, offb_gc, curb_gc, NB_GC, 1,
        cnt_gg,  off_gg,  cur_gg,  NG,    0);

    part3_kernel<<<576, 256, 0, stream>>>(
        src_cg, dst_cg, e_cg, curb_cg, ubkt_cg, cap_cg,
        src_gc, dst_gc, e_gc, curb_gc, ubkt_gc, cap_gc,
        src_gg, dst_gg, e_gg, cur_gg, bkt_gg);

    if (use_bf16) {
        gather3_kernel<true><<<NB_CG + NB_GC, 256, 0, stream>>>(
            ubkt_cg, cntb_cg, offb_cg, ubkt_gc, cntb_gc, offb_gc,
            (const void*)cf16, (const void*)gf16,
            w_cell, w_rev, w_gg, ci_gene, cii_gene, ci_cell,
            off_gg, bkt_gg, e_gg, g_out, c_out);
    } else {
        gather3_kernel<false><<<NB_CG + NB_GC, 256, 0, stream>>>(
            ubkt_cg, cntb_cg, offb_cg, ubkt_gc, cntb_gc, offb_gc,
            (const void*)c_feat, (const void*)g_feat,
            w_cell, w_rev, w_gg, ci_gene, cii_gene, ci_cell,
            off_gg, bkt_gg, e_gg, g_out, c_out);
    }
}

// Round 8
// 366.848 us; speedup vs baseline: 3.6355x; 1.0158x over previous
//
#include <hip/hip_runtime.h>

#define NC 50000
#define NG 3000
#define D  64

#define NB_CG 750   // gene bins of 4  (SHIFT 2)
#define NB_GC 782   // cell bins of 64 (SHIFT 6), 782*64 = 50048
#define PBITS 18
#define TILE  8192
#define NHIST 576
#define NPREP 128
#define CAPV  6144

__device__ inline unsigned short f2bf(float x) {
    unsigned u = __float_as_uint(x);
    unsigned r = u + 0x7FFFu + ((u >> 16) & 1u);
    return (unsigned short)(r >> 16);
}

// 8-lane row loader: lane l8 holds 8 consecutive-ish elements of row s.
// BF16 mapping: elements [8*l8, 8*l8+8). FP32 mapping: [4*l8,4*l8+4) and [32+4*l8, 36+4*l8).
template <bool BF16>
__device__ inline void row8(const void* feat, int s, int l8, float f[8]) {
    if (BF16) {
        const uint4 q = *((const uint4*)((const unsigned short*)feat + (size_t)s * D) + l8);
        f[0] = __uint_as_float(q.x << 16); f[1] = __uint_as_float(q.x & 0xFFFF0000u);
        f[2] = __uint_as_float(q.y << 16); f[3] = __uint_as_float(q.y & 0xFFFF0000u);
        f[4] = __uint_as_float(q.z << 16); f[5] = __uint_as_float(q.z & 0xFFFF0000u);
        f[6] = __uint_as_float(q.w << 16); f[7] = __uint_as_float(q.w & 0xFFFF0000u);
    } else {
        const float4* row = (const float4*)((const float*)feat + (size_t)s * D);
        const float4 a = row[l8];
        const float4 b = row[l8 + 8];
        f[0] = a.x; f[1] = a.y; f[2] = a.z; f[3] = a.w;
        f[4] = b.x; f[5] = b.y; f[6] = b.z; f[7] = b.w;
    }
}

// ======================= stage1: hist (cg|gc|gg) + prep + last-block scan =======================

__global__ __launch_bounds__(256) void stage1_kernel(
    const int* __restrict__ dst_cg, int e_cg, int* __restrict__ cnt_cg,
    const int* __restrict__ dst_gc, int e_gc, int* __restrict__ cnt_gc,
    const int* __restrict__ dst_gg, int e_gg, int* __restrict__ cnt_gg,
    int* __restrict__ off_cg, int* __restrict__ cur_cg,
    int* __restrict__ off_gc, int* __restrict__ cur_gc,
    int* __restrict__ off_gg, int* __restrict__ cur_gg,
    int* __restrict__ done,
    const float* __restrict__ cj_cell, const float* __restrict__ mask_exp,
    const float* __restrict__ cj_gene, const float* __restrict__ mask_rev,
    const float* __restrict__ cjj_gene, const float* __restrict__ mask_gg,
    float* __restrict__ w_cell, float* __restrict__ w_rev, float* __restrict__ w_gg,
    const float* __restrict__ c_feat, const float* __restrict__ g_feat,
    unsigned short* __restrict__ cf16, unsigned short* __restrict__ gf16, int do_cvt)
{
    const int tid = threadIdx.x;

    if (blockIdx.x >= NHIST) {              // ---- prep blocks ----
        const int pb = blockIdx.x - NHIST;
        const long long stride = (long long)NPREP * 256;
        for (long long i = (long long)pb * 256 + tid; i < NC; i += stride)
            w_cell[i] = cj_cell[i] * mask_exp[i];
        for (long long i = (long long)pb * 256 + tid; i < NG; i += stride) {
            w_rev[i] = cj_gene[i] * mask_rev[i];
            w_gg[i]  = cjj_gene[i] * mask_gg[i];
        }
        if (do_cvt) {
            const long long total8 = (long long)(NC + NG) * D / 8;
            for (long long t = (long long)pb * 256 + tid; t < total8; t += stride) {
                const long long base = t * 8;
                const float* sp; unsigned short* dp;
                if (base < (long long)NC * D) { sp = c_feat + base; dp = cf16 + base; }
                else { sp = g_feat + (base - (long long)NC * D); dp = gf16 + (base - (long long)NC * D); }
                const float4 a = ((const float4*)sp)[0];
                const float4 b = ((const float4*)sp)[1];
                ((ushort4*)dp)[0] = make_ushort4(f2bf(a.x), f2bf(a.y), f2bf(a.z), f2bf(a.w));
                ((ushort4*)dp)[1] = make_ushort4(f2bf(b.x), f2bf(b.y), f2bf(b.z), f2bf(b.w));
            }
        }
        return;
    }

    // ---- histogram blocks ----
    __shared__ int h[NG];                   // 12 KB, max of the three bin counts
    const int* dst; int* cnt; int ne, nbins, shift, bid, nblk;
    if (blockIdx.x < 256)      { dst = dst_cg; cnt = cnt_cg; ne = e_cg; nbins = NB_CG; shift = 2; bid = blockIdx.x;       nblk = 256; }
    else if (blockIdx.x < 512) { dst = dst_gc; cnt = cnt_gc; ne = e_gc; nbins = NB_GC; shift = 6; bid = blockIdx.x - 256; nblk = 256; }
    else                       { dst = dst_gg; cnt = cnt_gg; ne = e_gg; nbins = NG;    shift = 0; bid = blockIdx.x - 512; nblk = 64;  }
    for (int i = tid; i < nbins; i += 256) h[i] = 0;
    __syncthreads();
    for (long long e = (long long)bid * 256 + tid; e < ne; e += (long long)nblk * 256) {
        unsigned b = ((unsigned)dst[e]) >> shift;
        if (b < (unsigned)nbins) atomicAdd(&h[b], 1);
    }
    __syncthreads();
    for (int i = tid; i < nbins; i += 256) {
        int v = h[i];
        if (v) atomicAdd(&cnt[i], v);
    }

    // ---- last hist block performs the three scans ----
    __threadfence();
    __shared__ int lastflag;
    if (tid == 0) lastflag = (atomicAdd(done, 1) == NHIST - 1) ? 1 : 0;
    __syncthreads();
    if (!lastflag) return;
    __threadfence();

    __shared__ int s_wtot[4];
    __shared__ int s_woff[4];
    __shared__ int s_tot;
    __shared__ int s_carry;
    const int lane = tid & 63;
    const int wid  = tid >> 6;
    for (int a = 0; a < 3; ++a) {
        const int* c; int* o; int* u; int n; int pad;
        if (a == 0)      { c = cnt_cg; o = off_cg; u = cur_cg; n = NB_CG; pad = 1; }
        else if (a == 1) { c = cnt_gc; o = off_gc; u = cur_gc; n = NB_GC; pad = 1; }
        else             { c = cnt_gg; o = off_gg; u = cur_gg; n = NG;    pad = 0; }
        if (tid == 0) s_carry = 0;
        __syncthreads();
        for (int base = 0; base < n; base += 256) {
            int i = base + tid;
            int v = (i < n) ? c[i] : 0;
            if (pad) v = (v + 15) & ~15;
            int incl = v;
            #pragma unroll
            for (int d = 1; d < 64; d <<= 1) {
                int t = __shfl_up(incl, d);
                if (lane >= d) incl += t;
            }
            if (lane == 63) s_wtot[wid] = incl;
            __syncthreads();
            if (tid < 4) {
                int t = s_wtot[tid];
                int s = t;
                #pragma unroll
                for (int d = 1; d < 4; d <<= 1) {
                    int x = __shfl_up(s, d);
                    if (tid >= d) s += x;
                }
                s_woff[tid] = s - t;
                if (tid == 3) s_tot = s;
            }
            __syncthreads();
            int excl = incl - v + s_woff[wid] + s_carry;
            if (i < n) { o[i] = excl; u[i] = excl; }
            __syncthreads();
            if (tid == 0) s_carry += s_tot;
            __syncthreads();
        }
        if (tid == 0) o[n] = s_carry;
        __syncthreads();
    }
}

// ======================= fused partition (cg | gc) + gg fill =======================

__global__ __launch_bounds__(256) void part3_kernel(
    const int* __restrict__ src_cg, const int* __restrict__ dst_cg, int e_cg,
    int* __restrict__ cur_cg, unsigned* __restrict__ ubkt_cg, int cap_cg,
    const int* __restrict__ src_gc, const int* __restrict__ dst_gc, int e_gc,
    int* __restrict__ cur_gc, unsigned* __restrict__ ubkt_gc, int cap_gc,
    const int* __restrict__ src_gg, const int* __restrict__ dst_gg, int e_gg,
    int* __restrict__ cur_gg, int* __restrict__ bkt_gg)
{
    const int tid = threadIdx.x;
    if (blockIdx.x >= 512) {   // gg fill (64 blocks)
        for (long long e = (long long)(blockIdx.x - 512) * 256 + tid; e < e_gg;
             e += (long long)64 * 256) {
            int pos = atomicAdd(&cur_gg[dst_gg[e]], 1);
            if (pos >= 0 && pos < e_gg) bkt_gg[pos] = src_gg[e];
        }
        return;
    }
    const int* src; const int* dst; int ne; int* ccur; unsigned* bkt; int cap, shift, nbins, bid;
    if (blockIdx.x < 256) { src = src_cg; dst = dst_cg; ne = e_cg; ccur = cur_cg; bkt = ubkt_cg; cap = cap_cg; shift = 2; nbins = NB_CG; bid = blockIdx.x; }
    else                  { src = src_gc; dst = dst_gc; ne = e_gc; ccur = cur_gc; bkt = ubkt_gc; cap = cap_gc; shift = 6; nbins = NB_GC; bid = blockIdx.x - 256; }

    __shared__ int th[784];
    __shared__ int toff[784];
    __shared__ int tcur[784];
    __shared__ int gb[784];
    __shared__ unsigned staged[TILE];
    const unsigned PMASK = (1u << PBITS) - 1u;
    const unsigned DMASK = (1u << shift) - 1u;

    for (long long tbase = (long long)bid * TILE; tbase < ne;
         tbase += (long long)256 * TILE) {
        const int n = (int)((ne - tbase) < TILE ? (ne - tbase) : TILE);
        for (int i = tid; i < nbins; i += 256) { th[i] = 0; tcur[i] = 0; }
        __syncthreads();
        #pragma unroll 4
        for (int k = 0; k < 32; ++k) {
            int i = k * 256 + tid;
            if (i < n) {
                unsigned b = ((unsigned)dst[tbase + i]) >> shift;
                if (b < (unsigned)nbins) atomicAdd(&th[b], 1);
            }
        }
        __syncthreads();
        if (tid < 64) {
            int carry = 0;
            for (int c = 0; c < nbins; c += 64) {
                int idx = c + tid;
                int v = (idx < nbins) ? th[idx] : 0;
                int incl = v;
                #pragma unroll
                for (int d = 1; d < 64; d <<= 1) {
                    int t = __shfl_up(incl, d);
                    if (tid >= d) incl += t;
                }
                if (idx < nbins) toff[idx] = incl - v + carry;
                carry += __shfl(incl, 63);
            }
        }
        __syncthreads();
        for (int i = tid; i < nbins; i += 256) {
            int c = th[i];
            if (c) gb[i] = atomicAdd(&ccur[i], c);
        }
        __syncthreads();
        #pragma unroll 4
        for (int k = 0; k < 32; ++k) {
            int i = k * 256 + tid;
            if (i < n) {
                unsigned d = (unsigned)dst[tbase + i];
                unsigned s = (unsigned)src[tbase + i];
                unsigned b = d >> shift;
                if (b < (unsigned)nbins) {
                    int p = toff[b] + atomicAdd(&tcur[b], 1);
                    if (p >= 0 && p < TILE)
                        staged[p] = (b << PBITS) | (s << shift) | (d & DMASK);
                }
            }
        }
        __syncthreads();
        for (int i = tid; i < n; i += 256) {
            unsigned v = staged[i];
            unsigned b = v >> PBITS;
            long long g = (long long)gb[b] + (i - toff[b]);
            if (g >= 0 && g < cap) bkt[g] = v & PMASK;
        }
        __syncthreads();
    }
}

// ======================= fused gather (cg + gg fold | gc), src-tile-sorted =======================
// cg sort key = (dloc<<4) | (src>>12): each cell's walk ascends src tiles (512 KB each),
// so co-resident blocks sweep cf16 as a coherent L2-resident band.
template <bool BF16>
__global__ __launch_bounds__(256) void gather3_kernel(
    const unsigned* __restrict__ ubkt_cg, const int* __restrict__ cntb_cg, const int* __restrict__ offb_cg,
    const unsigned* __restrict__ ubkt_gc, const int* __restrict__ cntb_gc, const int* __restrict__ offb_gc,
    const void* __restrict__ cfeat, const void* __restrict__ gfeat,
    const float* __restrict__ w_cell, const float* __restrict__ w_rev, const float* __restrict__ w_gg,
    const float* __restrict__ ci_gene, const float* __restrict__ cii_gene, const float* __restrict__ ci_cell,
    const int* __restrict__ off_gg, const int* __restrict__ bkt_gg, int e_gg,
    float* __restrict__ g_out, float* __restrict__ c_out)
{
    __shared__ unsigned sorted[CAPV];
    __shared__ int lh[64];
    __shared__ int loff[64];
    __shared__ int lcur[64];

    const bool is_cg = (blockIdx.x < NB_CG);
    const int bin = is_cg ? blockIdx.x : blockIdx.x - NB_CG;
    const int n = (is_cg ? cntb_cg : cntb_gc)[bin];
    const long long base = (is_cg ? offb_cg : offb_gc)[bin];
    const unsigned* bkt = is_cg ? ubkt_cg : ubkt_gc;
    const void* feat = is_cg ? cfeat : gfeat;
    const float* wsrc = is_cg ? w_cell : w_rev;
    const int shift = is_cg ? 2 : 6;
    const int DIVv = is_cg ? 4 : 64;
    const int KPC  = is_cg ? 16 : 1;     // sort keys per cell
    const int tid  = threadIdx.x;
    const int lane = tid & 63;
    const int wid  = tid >> 6;
    const int grp8 = lane >> 3;          // 8 groups of 8 lanes -> 8 edges in flight
    const int l8   = lane & 7;
    const bool fast = (n <= CAPV);

    if (fast) {
        for (int i = tid; i < 64; i += 256) { lh[i] = 0; lcur[i] = 0; }
        __syncthreads();
        for (int i = tid; i < n; i += 256) {
            const unsigned v = bkt[base + i];
            const int k = is_cg ? (int)(((v & 3u) << 4) | (((v >> 2) & 0xFFFFu) >> 12))
                                : (int)(v & 63u);
            atomicAdd(&lh[k], 1);
        }
        __syncthreads();
        if (tid < 64) {
            int v = lh[tid];
            int incl = v;
            #pragma unroll
            for (int d = 1; d < 64; d <<= 1) {
                int t = __shfl_up(incl, d);
                if (tid >= d) incl += t;
            }
            loff[tid] = incl - v;
        }
        __syncthreads();
        for (int i = tid; i < n; i += 256) {
            const unsigned v = bkt[base + i];
            const int k = is_cg ? (int)(((v & 3u) << 4) | (((v >> 2) & 0xFFFFu) >> 12))
                                : (int)(v & 63u);
            int p = loff[k] + atomicAdd(&lcur[k], 1);
            if (p >= 0 && p < CAPV) sorted[p] = v;
        }
        __syncthreads();
    }

    for (int cell = wid; cell < DIVv; cell += 4) {
        const int r = (bin << shift) + cell;
        if (r >= (is_cg ? NG : NC)) continue;

        float fA[8] = {0.f, 0.f, 0.f, 0.f, 0.f, 0.f, 0.f, 0.f};
        if (fast) {
            const int k0 = cell * KPC, k1 = k0 + KPC - 1;
            const int lo = loff[k0], hi = loff[k1] + lh[k1];
            for (int jj = lo; jj < hi; jj += 8) {
                const int j = jj + grp8;
                const bool valid = (j < hi);
                const unsigned v = valid ? sorted[j] : 0u;
                const int s = (v >> shift) & 0xFFFF;
                const float w = valid ? wsrc[s] : 0.0f;
                float f[8]; row8<BF16>(feat, s, l8, f);
                #pragma unroll
                for (int q = 0; q < 8; ++q) fA[q] += w * f[q];
            }
        } else {
            for (int jj = 0; jj < n; jj += 8) {
                const int j = jj + grp8;
                const bool valid = (j < n);
                const unsigned v = valid ? bkt[base + j] : 0u;
                const bool ok = valid && ((int)(v & (unsigned)(DIVv - 1)) == cell);
                const int s = (v >> shift) & 0xFFFF;
                const float w = ok ? wsrc[s] : 0.0f;
                float f[8]; row8<BF16>(feat, s, l8, f);
                #pragma unroll
                for (int q = 0; q < 8; ++q) fA[q] += w * f[q];
            }
        }

        float fB[8] = {0.f, 0.f, 0.f, 0.f, 0.f, 0.f, 0.f, 0.f};
        if (is_cg) {
            int lo2 = off_gg[r], hi2 = off_gg[r + 1];
            lo2 = lo2 < 0 ? 0 : (lo2 > e_gg ? e_gg : lo2);
            hi2 = hi2 < 0 ? 0 : (hi2 > e_gg ? e_gg : hi2);
            for (int jj = lo2; jj < hi2; jj += 8) {
                const int j = jj + grp8;
                const bool valid = (j < hi2);
                const int s = valid ? bkt_gg[j] : 0;
                const float w = valid ? w_gg[s] : 0.0f;
                float f[8]; row8<BF16>(gfeat, s, l8, f);
                #pragma unroll
                for (int q = 0; q < 8; ++q) fB[q] += w * f[q];
            }
        }

        #pragma unroll
        for (int q = 0; q < 8; ++q) {
            #pragma unroll
            for (int off = 8; off < 64; off <<= 1) fA[q] += __shfl_xor(fA[q], off);
        }
        if (is_cg) {
            #pragma unroll
            for (int q = 0; q < 8; ++q) {
                #pragma unroll
                for (int off = 8; off < 64; off <<= 1) fB[q] += __shfl_xor(fB[q], off);
            }
        }

        if (grp8 == 0) {
            float o[8];
            float* outp;
            if (is_cg) {
                const float sa = 0.5f * ci_gene[r];
                const float sb = 0.5f * cii_gene[r];
                outp = g_out + (size_t)r * D;
                #pragma unroll
                for (int q = 0; q < 8; ++q) o[q] = sa * fA[q] + sb * fB[q];
            } else {
                const float sc = ci_cell[r];
                outp = c_out + (size_t)r * D;
                #pragma unroll
                for (int q = 0; q < 8; ++q) o[q] = sc * fA[q];
            }
            if (BF16) {
                *(float4*)(outp + 8 * l8)     = make_float4(o[0], o[1], o[2], o[3]);
                *(float4*)(outp + 8 * l8 + 4) = make_float4(o[4], o[5], o[6], o[7]);
            } else {
                *(float4*)(outp + 4 * l8)      = make_float4(o[0], o[1], o[2], o[3]);
                *(float4*)(outp + 32 + 4 * l8) = make_float4(o[4], o[5], o[6], o[7]);
            }
        }
    }
}

// ======================= fallback (atomic scatter) =======================

__global__ __launch_bounds__(256) void edge_scatter_kernel(
    const float* __restrict__ feat, const float* __restrict__ cj,
    const float* __restrict__ mask, const float* __restrict__ ci,
    const int* __restrict__ src, const int* __restrict__ dst,
    float* __restrict__ out, int nedges, float alpha)
{
    const int lane16 = threadIdx.x & 15;
    const int eloc   = threadIdx.x >> 4;
    const long long e = (long long)blockIdx.x * 16 + eloc;
    if (e >= nedges) return;
    const int s = src[e];
    const int t = dst[e];
    const float w = cj[s] * mask[s] * ci[t] * alpha;
    const float4 v = *(const float4*)(feat + (size_t)s * D + lane16 * 4);
    float* o = out + (size_t)t * D + lane16 * 4;
#if defined(__HIP_DEVICE_COMPILE__)
    unsafeAtomicAdd(o + 0, w * v.x);
    unsafeAtomicAdd(o + 1, w * v.y);
    unsafeAtomicAdd(o + 2, w * v.z);
    unsafeAtomicAdd(o + 3, w * v.w);
#endif
}

// ======================= launch =======================

extern "C" void kernel_launch(void* const* d_in, const int* in_sizes, int n_in,
                              void* d_out, int out_size, void* d_ws, size_t ws_size,
                              hipStream_t stream)
{
    const float* c_feat   = (const float*)d_in[0];
    const float* g_feat   = (const float*)d_in[1];
    const float* cj_cell  = (const float*)d_in[2];
    const float* ci_cell  = (const float*)d_in[3];
    const float* cj_gene  = (const float*)d_in[4];
    const float* ci_gene  = (const float*)d_in[5];
    const float* cjj_gene = (const float*)d_in[6];
    const float* cii_gene = (const float*)d_in[7];
    const float* mask_exp = (const float*)d_in[8];
    const float* mask_rev = (const float*)d_in[9];
    const float* mask_gg  = (const float*)d_in[10];
    const int*   src_cg   = (const int*)d_in[11];
    const int*   dst_cg   = (const int*)d_in[12];
    const int*   src_gc   = (const int*)d_in[13];
    const int*   dst_gc   = (const int*)d_in[14];
    const int*   src_gg   = (const int*)d_in[15];
    const int*   dst_gg   = (const int*)d_in[16];

    const int e_cg = in_sizes[11];
    const int e_gc = in_sizes[13];
    const int e_gg = in_sizes[15];

    float* c_out = (float*)d_out;                   // [NC, D]
    float* g_out = (float*)d_out + (size_t)NC * D;  // [NG, D]

    const int cap_cg = e_cg + 16 * NB_CG;
    const int cap_gc = e_gc + 16 * NB_GC;

    // ---- workspace layout (int units) ----
    int* ws = (int*)d_ws;
    size_t p = 0;
    int* cntb_cg = ws + p; p += NB_CG;
    int* cntb_gc = ws + p; p += NB_GC;
    int* cnt_gg  = ws + p; p += NG;
    int* done    = ws + p; p += 1;         // counts+done contiguous -> one memset
    int* offb_cg = ws + p; p += NB_CG + 1;
    int* offb_gc = ws + p; p += NB_GC + 1;
    int* off_gg  = ws + p; p += NG + 1;
    int* curb_cg = ws + p; p += NB_CG;
    int* curb_gc = ws + p; p += NB_GC;
    int* cur_gg  = ws + p; p += NG;
    float* w_cell = (float*)(ws + p); p += NC;
    float* w_rev  = (float*)(ws + p); p += NG;
    float* w_gg   = (float*)(ws + p); p += NG;
    unsigned* ubkt_cg = (unsigned*)(ws + p); p += cap_cg;
    unsigned* ubkt_gc = (unsigned*)(ws + p); p += cap_gc;
    int* bkt_gg = ws + p; p += e_gg;
    const size_t need_base = p * sizeof(int);
    unsigned short* cf16 = (unsigned short*)(ws + p); p += (size_t)NC * D / 2;
    unsigned short* gf16 = (unsigned short*)(ws + p); p += (size_t)NG * D / 2;
    const size_t need_full = p * sizeof(int);

    if (need_base > ws_size) {
        hipMemsetAsync(d_out, 0, (size_t)out_size * sizeof(float), stream);
        edge_scatter_kernel<<<(e_cg + 15) / 16, 256, 0, stream>>>(
            c_feat, cj_cell, mask_exp, ci_gene, src_cg, dst_cg, g_out, e_cg, 0.5f);
        edge_scatter_kernel<<<(e_gc + 15) / 16, 256, 0, stream>>>(
            g_feat, cj_gene, mask_rev, ci_cell, src_gc, dst_gc, c_out, e_gc, 1.0f);
        edge_scatter_kernel<<<(e_gg + 15) / 16, 256, 0, stream>>>(
            g_feat, cjj_gene, mask_gg, cii_gene, src_gg, dst_gg, g_out, e_gg, 0.5f);
        return;
    }
    const int use_bf16 = (need_full <= ws_size) ? 1 : 0;

    hipMemsetAsync(cntb_cg, 0, (size_t)(NB_CG + NB_GC + NG + 1) * sizeof(int), stream);

    stage1_kernel<<<NHIST + NPREP, 256, 0, stream>>>(
        dst_cg, e_cg, cntb_cg, dst_gc, e_gc, cntb_gc, dst_gg, e_gg, cnt_gg,
        offb_cg, curb_cg, offb_gc, curb_gc, off_gg, cur_gg, done,
        cj_cell, mask_exp, cj_gene, mask_rev, cjj_gene, mask_gg,
        w_cell, w_rev, w_gg, c_feat, g_feat, cf16, gf16, use_bf16);

    part3_kernel<<<576, 256, 0, stream>>>(
        src_cg, dst_cg, e_cg, curb_cg, ubkt_cg, cap_cg,
        src_gc, dst_gc, e_gc, curb_gc, ubkt_gc, cap_gc,
        src_gg, dst_gg, e_gg, cur_gg, bkt_gg);

    if (use_bf16) {
        gather3_kernel<true><<<NB_CG + NB_GC, 256, 0, stream>>>(
            ubkt_cg, cntb_cg, offb_cg, ubkt_gc, cntb_gc, offb_gc,
            (const void*)cf16, (const void*)gf16,
            w_cell, w_rev, w_gg, ci_gene, cii_gene, ci_cell,
            off_gg, bkt_gg, e_gg, g_out, c_out);
    } else {
        gather3_kernel<false><<<NB_CG + NB_GC, 256, 0, stream>>>(
            ubkt_cg, cntb_cg, offb_cg, ubkt_gc, cntb_gc, offb_gc,
            (const void*)c_feat, (const void*)g_feat,
            w_cell, w_rev, w_gg, ci_gene, cii_gene, ci_cell,
            off_gg, bkt_gg, e_gg, g_out, c_out);
    }
}